// Round 13
// baseline (127.466 us; speedup 1.0000x reference)
//
#include <hip/hip_runtime.h>
#include <hip/hip_bf16.h>

#define NMAX 64
#define LDA 65   // +1 pad: conflict-free row and column access

// ---- cross-lane helpers ----
__device__ __forceinline__ double readlane_d(double x, int l) {
    const int lo = __builtin_amdgcn_readlane(__double2loint(x), l);
    const int hi = __builtin_amdgcn_readlane(__double2hiint(x), l);
    return __hiloint2double(hi, lo);
}
__device__ __forceinline__ float readlane_f(float x, int l) {
    return __int_as_float(__builtin_amdgcn_readlane(__float_as_int(x), l));
}
template <int CTRL>
__device__ __forceinline__ unsigned dpp_umin(unsigned x) {
    const unsigned t = (unsigned)__builtin_amdgcn_update_dpp(0, (int)x, CTRL, 0xF, 0xF, true);
    return x < t ? x : t;          // folds to v_min_u32_dpp
}
__device__ __forceinline__ unsigned dpp_umin6(unsigned x) {  // lane63 = global min
    x = dpp_umin<0xB1>(x);  x = dpp_umin<0x4E>(x);
    x = dpp_umin<0x141>(x); x = dpp_umin<0x140>(x);
    x = dpp_umin<0x142>(x); x = dpp_umin<0x143>(x);
    return x;
}
template <int CTRL>
__device__ __forceinline__ double dpp_add_step(double x) {
    const int lo = __builtin_amdgcn_update_dpp(0, __double2loint(x), CTRL, 0xF, 0xF, true);
    const int hi = __builtin_amdgcn_update_dpp(0, __double2hiint(x), CTRL, 0xF, 0xF, true);
    return x + __hiloint2double(hi, lo);
}
__device__ __forceinline__ double wave_sum_f64(double x) {   // exact, each lane once
    x = dpp_add_step<0xB1>(x);  x = dpp_add_step<0x4E>(x);
    x = dpp_add_step<0x141>(x); x = dpp_add_step<0x140>(x);
    x = dpp_add_step<0x142>(x); x = dpp_add_step<0x143>(x);
    return readlane_d(x, 63);
}
// mask-lane ? a : b (mask = wave-uniform 64-bit value in SGPRs)
__device__ __forceinline__ unsigned sel_u32(unsigned long long m, unsigned a, unsigned b) {
    unsigned r;
    asm("v_cndmask_b32 %0, %1, %2, %3" : "=v"(r) : "v"(b), "v"(a), "s"(m));
    return r;
}
__device__ __forceinline__ float sel_f32(unsigned long long m, float a, float b) {
    return __int_as_float((int)sel_u32(m, (unsigned)__float_as_int(a),
                                          (unsigned)__float_as_int(b)));
}
__device__ __forceinline__ int sel_i32(unsigned long long m, int a, int b) {
    return (int)sel_u32(m, (unsigned)a, (unsigned)b);
}

// One wave (64 lanes) per batch: Jonker-Volgenant LAP, distance formulation,
// full f32, matrix in padded LDS (single ds_read_b32 row fetch — replaces the
// R12 register-matrix dynamic extract that lowered to an AGPR select waterfall).
// FULL JV init: column reduction + greedy zero matching + augmenting row
// reduction (ARR). Selection via packed-key (value|lane) u32 DPP min: one
// reduce chain + one readlane gives argmin and (6-bit-truncated) delta;
// distances clamped >= 0 keep uint ordering valid. Decision arithmetic is
// identical to R12 (verified absmax 0.0).
__global__ __launch_bounds__(64, 2) void hung_loss_kernel(
    const float* __restrict__ pred, const float* __restrict__ gt,
    const int* __restrict__ n1s, const int* __restrict__ n2s,
    double* __restrict__ partial)
{
    const int b = blockIdx.x;
    const int lane = threadIdx.x & 63;
    const float* __restrict__ predb = pred + (size_t)b * NMAX * NMAX;
    const float* __restrict__ gtb   = gt   + (size_t)b * NMAX * NMAX;
    const int n1 = n1s[b];
    const int n2 = n2s[b];
    const bool trans = (n1 > n2);                  // lap requires n <= m
    const int n = trans ? n2 : n1;
    const int m = trans ? n1 : n2;
    const float FINF  = __int_as_float(0x7f800000);
    const float FNINF = __int_as_float(0xff800000);
    const unsigned NEGINF32 = 0xFF800000u;

    // ---- stage LAP matrix into padded LDS: A[r*LDA+c] = lap[r][c] ----
    __shared__ float A[NMAX * LDA];
    __shared__ int mincol[NMAX];
    mincol[lane] = 127;
    {
        const float4* p4 = (const float4*)predb;
        #pragma unroll
        for (int it = 0; it < 16; ++it) {
            const float4 val = p4[it * 64 + lane];
            const int r = it * 4 + (lane >> 4);    // source row in pred
            const int c = (lane & 15) * 4;         // source col in pred
            if (!trans) {
                A[r * LDA + c + 0] = val.x; A[r * LDA + c + 1] = val.y;
                A[r * LDA + c + 2] = val.z; A[r * LDA + c + 3] = val.w;
            } else {
                A[(c + 0) * LDA + r] = val.x; A[(c + 1) * LDA + r] = val.y;
                A[(c + 2) * LDA + r] = val.z; A[(c + 3) * LDA + r] = val.w;
            }
        }
    }
    __syncthreads();

    // ---- column reduction over real rows (r < n): v = -max, argmax row am ----
    float v;
    int am = 0;
    {
        float mx = FNINF;
        for (int r = 0; r < n; ++r) {              // consecutive dwords: conflict-free
            const float a = A[r * LDA + lane];
            const bool take = a > mx;              // strict > : first occurrence
            mx = take ? a : mx;
            am = take ? r : am;
        }
        v = (lane < m) ? (-mx) : 0.0f;
    }

    // ---- greedy zero-edge matching: column j -> row am(j), first column wins
    if (lane < m) atomicMin(&mincol[am], lane);
    __syncthreads();
    const bool matched = (lane < m) && (mincol[am] == lane);
    int p = matched ? (am + 1) : 0;                // column-side matching (1-based)
    const unsigned long long rowsM =
        __ballot((lane < n) && (mincol[lane] != 127));
    unsigned long long freerows =
        (~rowsM) & ((n == 64) ? ~0ull : ((1ull << n) - 1ull));

    float u = 0.0f;      // lane r owns u[r+1] (row dual)
    float uent = 0.0f;   // entry distance of row lane+1 (valid when on tree)
    float dsel = 0.0f;   // selected distance of column lane+1 (valid when used)
    const unsigned long long fake = (m < 64) ? (~0ull << m) : 0ull;
    const unsigned VMASK = 0xFFFFFFC0u;            // value part of packed key

    // ---- augmenting row reduction (ARR): resolve most free rows cheaply ----
    {
        int steps = 0;
        while (freerows && steps < 128) {
            ++steps;
            const int i = __ffsll(freerows);       // 1-based free row
            freerows &= freerows - 1;
            float a = A[(i - 1) * LDA + lane];     // ds_read_b32, conflict-free
            a = __int_as_float((int)sel_u32(fake, NEGINF32, __float_as_int(a)));
            float r_ = (0.0f - a) - v;             // reduced cost (u_i treated 0)
            r_ = fmaxf(r_, 0.0f);                  // clamp drift; keeps uint order
            const unsigned key1 = (__float_as_uint(r_) & VMASK) | (unsigned)lane;
            const unsigned K1 = (unsigned)__builtin_amdgcn_readlane((int)dpp_umin6(key1), 63);
            const int j1 = (int)(K1 & 63u) + 1;
            const unsigned key2 = sel_u32(1ull << (j1 - 1), 0xFFFFFFFFu, key1);
            const unsigned K2 = (unsigned)__builtin_amdgcn_readlane((int)dpp_umin6(key2), 63);
            const unsigned u1b = K1 & VMASK, u2b = K2 & VMASK;
            const float u2f = __uint_as_float(u2b);
            int jt = j1;
            int i0k = __builtin_amdgcn_readlane(p, j1 - 1);
            if (u1b < u2b) {                       // unique min: tighten v[j1]
                const float u1f = __uint_as_float(u1b);
                v = sel_f32(1ull << (j1 - 1), v - (u2f - u1f), v);
            } else if (i0k != 0) {                 // tie and j1 taken: use j2
                jt = (int)(K2 & 63u) + 1;
                i0k = __builtin_amdgcn_readlane(p, jt - 1);
            }
            p = sel_i32(1ull << (jt - 1), i, p);   // assign row i to column jt
            u = sel_f32(1ull << (i - 1), u2f, u);  // u[i] = u2 (CS + feasible)
            if (i0k != 0) freerows |= 1ull << (i0k - 1);   // kicked row rejoins
        }
    }

    // ---- Dijkstra phases for remaining free rows ----
    while (freerows) {
        const int i = __ffsll(freerows);           // 1-based free row
        freerows &= freerows - 1;
        unsigned long long um = fake;              // used (selected) + fake columns
        unsigned long long rowm = 1ull << (i - 1); // rows on the tree
        float d = FINF;                            // tentative distances
        int way = 0;                               // tree parent column (0=root)
        int vj0 = 0;                               // previous j1 (VGPR copy)
        float s = 0.0f - readlane_f(u, i - 1);     // s = D(i0) - u0[i0]
        uent = sel_f32(rowm, 0.0f, uent);          // root row entry distance = 0
        float aval = A[(i - 1) * LDA + lane];      // row i
        aval = __int_as_float((int)sel_u32(um, NEGINF32, __float_as_int(aval)));
        int j1f = 0;
        float DT = 0.0f;
        for (int guard = 0; guard < NMAX; ++guard) {
            const float r_ = (0.0f - aval) - v;    // used/fake -> +inf
            const float cur = fmaxf(r_ + s, 0.0f); // clamp: keys stay ordered
            const float dn = fminf(d, cur);
            const unsigned key = (__float_as_uint(dn) & VMASK) | (unsigned)lane;
            const unsigned K = (unsigned)__builtin_amdgcn_readlane((int)dpp_umin6(key), 63);
            const int j1 = (int)(K & 63u) + 1;
            const int i0n = __builtin_amdgcn_readlane(p, j1 - 1); // p[j1]; 0 => free
            const float H = __uint_as_float(K & VMASK);           // delta (trunc)
            const unsigned long long mj = 1ull << (j1 - 1);
            const bool lt = cur < d;
            way  = lt ? vj0 : way;
            dsel = sel_f32(mj, dn, dsel);          // record selected distance
            d    = sel_f32(mj, FINF, dn);          // destroy selected column
            if (i0n == 0) { j1f = j1; DT = H; break; }
            um |= mj;
            rowm |= 1ull << (i0n - 1);
            uent = sel_f32(1ull << (i0n - 1), H, uent);   // row entry distance
            s = H - readlane_f(u, i0n - 1);
            aval = A[(i0n - 1) * LDA + lane];      // next row fetch (single ds_read)
            aval = __int_as_float((int)sel_u32(um, NEGINF32, __float_as_int(aval)));
            vj0 = j1;
        }
        // ---- phase-end dual updates (equivalent to per-iteration +=/-=) ----
        v = sel_f32(um,   v + (dsel - DT), v);     // used columns
        u = sel_f32(rowm, u + (DT - uent), u);     // tree rows
        // ---- augment along way[] back to the root ----
        int j0 = j1f;
        while (j0 > 0) {
            const int j1w = __builtin_amdgcn_readlane(way, j0 - 1);
            const int newp = (j1w == 0) ? i : __builtin_amdgcn_readlane(p, j1w - 1);
            p = sel_i32(1ull << (j0 - 1), newp, p);
            j0 = j1w;
        }
    }

    // ---- fused loss: dis[i][j] from lane-held p; BCE in f32 like reference ----
    double lsum = 0.0;
    if (!trans) {
        for (int i2 = 0; i2 < NMAX; ++i2) {
            const float pv = A[i2 * LDA + lane];   // lap == pred layout (LDS hot)
            const float gv = gtb[i2 * NMAX + lane];
            const float dis = (p == i2 + 1) ? 1.0f : 0.0f;
            float ali = dis + gv;
            if (ali > 1.0f) ali = 0.9f;
            const float pp = ali * pv;
            const float gg = ali * gv;
            const float lp  = fmaxf(logf(pp),    -100.0f);
            const float l1p = fmaxf(log1pf(-pp), -100.0f);
            const float bce = -(gg * lp + (1.0f - gg) * l1p);
            if (i2 < n1 && lane < n2) lsum += (double)bce;
        }
    } else {
        for (int i2 = 0; i2 < NMAX; ++i2) {
            const float pv = predb[i2 * NMAX + lane];
            const float gv = gtb[i2 * NMAX + lane];
            const int pi = __builtin_amdgcn_readlane(p, i2);
            const float dis = (pi - 1 == lane) ? 1.0f : 0.0f;
            float ali = dis + gv;
            if (ali > 1.0f) ali = 0.9f;
            const float pp = ali * pv;
            const float gg = ali * gv;
            const float lp  = fmaxf(logf(pp),    -100.0f);
            const float l1p = fmaxf(log1pf(-pp), -100.0f);
            const float bce = -(gg * lp + (1.0f - gg) * l1p);
            if (i2 < n1 && lane < n2) lsum += (double)bce;
        }
    }
    const double tsum = wave_sum_f64(lsum);
    if (lane == 0) partial[b] = tsum;
}

__global__ __launch_bounds__(256) void finalize_kernel(
    const double* __restrict__ partial, const int* __restrict__ n1s,
    float* __restrict__ out, int B)
{
    __shared__ double sred[256];
    __shared__ int    nred[256];
    const int t = threadIdx.x;
    double s = 0.0;
    int ns = 0;
    for (int bb = t; bb < B; bb += 256) { s += partial[bb]; ns += n1s[bb]; }
    sred[t] = s; nred[t] = ns;
    __syncthreads();
    for (int off = 128; off >= 1; off >>= 1) {
        if (t < off) { sred[t] += sred[t + off]; nred[t] += nred[t + off]; }
        __syncthreads();
    }
    if (t == 0) out[0] = (float)sred[0] / (float)nred[0];
}

extern "C" void kernel_launch(void* const* d_in, const int* in_sizes, int n_in,
                              void* d_out, int out_size, void* d_ws, size_t ws_size,
                              hipStream_t stream) {
    const float* pred = (const float*)d_in[0];   // [B,64,64] f32
    const float* gt   = (const float*)d_in[1];   // [B,64,64] f32
    const int* n1s    = (const int*)d_in[2];     // [B] i32
    const int* n2s    = (const int*)d_in[3];     // [B] i32
    float* out = (float*)d_out;                  // scalar f32
    double* partial = (double*)d_ws;             // B doubles (16 KB)
    const int B = in_sizes[2];

    hung_loss_kernel<<<B, 64, 0, stream>>>(pred, gt, n1s, n2s, partial);
    finalize_kernel<<<1, 256, 0, stream>>>(partial, n1s, out, B);
}

// Round 14
// 117.057 us; speedup vs baseline: 1.0889x; 1.0889x over previous
//
#include <hip/hip_runtime.h>
#include <hip/hip_bf16.h>

#define NMAX 64

typedef float f32x32 __attribute__((ext_vector_type(32)));

// ---- cross-lane helpers ----
__device__ __forceinline__ double readlane_d(double x, int l) {
    const int lo = __builtin_amdgcn_readlane(__double2loint(x), l);
    const int hi = __builtin_amdgcn_readlane(__double2hiint(x), l);
    return __hiloint2double(hi, lo);
}
__device__ __forceinline__ float readlane_f(float x, int l) {
    return __int_as_float(__builtin_amdgcn_readlane(__float_as_int(x), l));
}
template <int CTRL>
__device__ __forceinline__ unsigned dpp_umin(unsigned x) {
    const unsigned t = (unsigned)__builtin_amdgcn_update_dpp(0, (int)x, CTRL, 0xF, 0xF, true);
    return x < t ? x : t;          // folds to v_min_u32_dpp
}
__device__ __forceinline__ unsigned dpp_umin6(unsigned x) {  // lane63 = global min
    x = dpp_umin<0xB1>(x);  x = dpp_umin<0x4E>(x);
    x = dpp_umin<0x141>(x); x = dpp_umin<0x140>(x);
    x = dpp_umin<0x142>(x); x = dpp_umin<0x143>(x);
    return x;
}
template <int CTRL>
__device__ __forceinline__ double dpp_add_step(double x) {
    const int lo = __builtin_amdgcn_update_dpp(0, __double2loint(x), CTRL, 0xF, 0xF, true);
    const int hi = __builtin_amdgcn_update_dpp(0, __double2hiint(x), CTRL, 0xF, 0xF, true);
    return x + __hiloint2double(hi, lo);
}
__device__ __forceinline__ double wave_sum_f64(double x) {   // exact, each lane once
    x = dpp_add_step<0xB1>(x);  x = dpp_add_step<0x4E>(x);
    x = dpp_add_step<0x141>(x); x = dpp_add_step<0x140>(x);
    x = dpp_add_step<0x142>(x); x = dpp_add_step<0x143>(x);
    return readlane_d(x, 63);
}
// mask-lane ? a : b (mask = wave-uniform 64-bit value in SGPRs)
__device__ __forceinline__ unsigned sel_u32(unsigned long long m, unsigned a, unsigned b) {
    unsigned r;
    asm("v_cndmask_b32 %0, %1, %2, %3" : "=v"(r) : "v"(b), "v"(a), "s"(m));
    return r;
}
__device__ __forceinline__ float sel_f32(unsigned long long m, float a, float b) {
    return __int_as_float((int)sel_u32(m, (unsigned)__float_as_int(a),
                                          (unsigned)__float_as_int(b)));
}
__device__ __forceinline__ int sel_i32(unsigned long long m, int a, int b) {
    return (int)sel_u32(m, (unsigned)a, (unsigned)b);
}
// uniform dynamic extract from the 64-deep register column
__device__ __forceinline__ float mat_get(const f32x32& lo, const f32x32& hi, int rr) {
    const float aL = lo[rr & 31], aH = hi[rr & 31];
    return (rr & 32) ? aH : aL;
}

// One wave (64 lanes) per batch: Jonker-Volgenant LAP, distance formulation,
// full f32, register-resident matrix (R12-verified fetch), FULL JV init:
// column reduction + greedy zero matching + PAIRED augmenting row reduction
// (two independent ARR rows per step; row B accepted iff its final target
// column differs from row A's — proof: A only lowers v[jtA], so B's stale-
// price argmin/second are unaffected at all other columns; B's matched slack
// stays exactly 0 and feasibility holds; collision -> B retries).
// Selection via packed-key (value|lane) u32 DPP min (6-bit-truncated delta,
// distances clamped >= 0). Decision arithmetic otherwise identical to R12
// (verified absmax 0.0).
__global__ __launch_bounds__(64, 2) void hung_loss_kernel(
    const float* __restrict__ pred, const float* __restrict__ gt,
    const int* __restrict__ n1s, const int* __restrict__ n2s,
    double* __restrict__ partial)
{
    const int b = blockIdx.x;
    const int lane = threadIdx.x & 63;
    const float* __restrict__ predb = pred + (size_t)b * NMAX * NMAX;
    const float* __restrict__ gtb   = gt   + (size_t)b * NMAX * NMAX;
    const int n1 = n1s[b];
    const int n2 = n2s[b];
    const bool trans = (n1 > n2);                  // lap requires n <= m
    const int n = trans ? n2 : n1;
    const int m = trans ? n1 : n2;
    const float FINF  = __int_as_float(0x7f800000);
    const float FNINF = __int_as_float(0xff800000);
    const unsigned NEGINF32 = 0xFF800000u;

    // ---- load LAP matrix into registers: lane j holds lap[:, j] (64 f32) ----
    f32x32 alo, ahi;
    if (!trans) {                                  // lap == scores
        #pragma unroll
        for (int r = 0; r < 32; ++r) alo[r] = predb[r * NMAX + lane];
        #pragma unroll
        for (int r = 0; r < 32; ++r) ahi[r] = predb[(r + 32) * NMAX + lane];
    } else {                                       // lap = scores^T
        #pragma unroll
        for (int r = 0; r < 32; ++r) alo[r] = predb[lane * NMAX + r];
        #pragma unroll
        for (int r = 0; r < 32; ++r) ahi[r] = predb[lane * NMAX + 32 + r];
    }
    if (lane >= m) {                               // fake columns: cost -> -inf
        #pragma unroll
        for (int r = 0; r < 32; ++r) { alo[r] = FNINF; ahi[r] = FNINF; }
    }

    // ---- column reduction over real rows (r < n): v = -max, argmax row am ----
    float v;
    int am = 0;
    {
        float mx = FNINF;
        #pragma unroll
        for (int r = 0; r < 32; ++r) {
            const bool take = (r < n) && (alo[r] > mx);
            mx = take ? alo[r] : mx;
            am = take ? r : am;
        }
        #pragma unroll
        for (int r = 0; r < 32; ++r) {
            const bool take = ((r + 32) < n) && (ahi[r] > mx);
            mx = take ? ahi[r] : mx;
            am = take ? (r + 32) : am;
        }
        v = (lane < m) ? (-mx) : 0.0f;
    }

    // ---- greedy zero-edge matching: column j -> row am(j), first column wins
    __shared__ int mincol[NMAX];
    mincol[lane] = 127;
    __syncthreads();
    if (lane < m) atomicMin(&mincol[am], lane);
    __syncthreads();
    const bool matched = (lane < m) && (mincol[am] == lane);
    int p = matched ? (am + 1) : 0;                // column-side matching (1-based)
    const unsigned long long rowsM =
        __ballot((lane < n) && (mincol[lane] != 127));
    unsigned long long freerows =
        (~rowsM) & ((n == 64) ? ~0ull : ((1ull << n) - 1ull));

    float u = 0.0f;      // lane r owns u[r+1] (row dual)
    float uent = 0.0f;   // entry distance of row lane+1 (valid when on tree)
    float dsel = 0.0f;   // selected distance of column lane+1 (valid when used)
    const unsigned VMASK = 0xFFFFFFC0u;            // value part of packed key

    // ---- PAIRED augmenting row reduction (ARR) ----
    {
        int steps = 0;
        while (freerows && steps < 128) {
            const int iA = __ffsll(freerows); freerows &= freerows - 1;
            const int iB = freerows ? __ffsll(freerows) : 0;
            if (iB) freerows &= freerows - 1;
            steps += (iB ? 2 : 1);

            // row A reduced costs
            const float aA = mat_get(alo, ahi, iA - 1);
            const float rA = fmaxf((0.0f - aA) - v, 0.0f);
            const unsigned keyA = (__float_as_uint(rA) & VMASK) | (unsigned)lane;
            // row B reduced costs (independent chain)
            unsigned keyB = 0;
            if (iB) {
                const float aB = mat_get(alo, ahi, iB - 1);
                const float rB = fmaxf((0.0f - aB) - v, 0.0f);
                keyB = (__float_as_uint(rB) & VMASK) | (unsigned)lane;
            }
            // first-min reduces (A and B interleave in the scheduler)
            const unsigned K1A = (unsigned)__builtin_amdgcn_readlane((int)dpp_umin6(keyA), 63);
            unsigned K1B = 0;
            if (iB) K1B = (unsigned)__builtin_amdgcn_readlane((int)dpp_umin6(keyB), 63);
            const int j1A = (int)(K1A & 63u) + 1;
            const int j1B = iB ? ((int)(K1B & 63u) + 1) : 0;
            // second-min reduces
            const unsigned key2A = sel_u32(1ull << (j1A - 1), 0xFFFFFFFFu, keyA);
            const unsigned K2A = (unsigned)__builtin_amdgcn_readlane((int)dpp_umin6(key2A), 63);
            unsigned K2B = 0;
            if (iB) {
                const unsigned key2B = sel_u32(1ull << (j1B - 1), 0xFFFFFFFFu, keyB);
                K2B = (unsigned)__builtin_amdgcn_readlane((int)dpp_umin6(key2B), 63);
            }

            // ---- resolve A (exact R12 logic) ----
            const unsigned u1A = K1A & VMASK, u2A = K2A & VMASK;
            const float u2fA = __uint_as_float(u2A);
            int jtA = j1A;
            int kickA = __builtin_amdgcn_readlane(p, j1A - 1);
            if (u1A < u2A) {                       // unique min: tighten v[j1A]
                v = sel_f32(1ull << (j1A - 1), v - (u2fA - __uint_as_float(u1A)), v);
            } else if (kickA != 0) {               // tie and j1A taken: use second
                jtA = (int)(K2A & 63u) + 1;
                kickA = __builtin_amdgcn_readlane(p, jtA - 1);
            }
            p = sel_i32(1ull << (jtA - 1), iA, p); // assign row iA to column jtA
            u = sel_f32(1ull << (iA - 1), u2fA, u);
            if (kickA != 0) freerows |= 1ull << (kickA - 1);

            // ---- resolve B iff final target differs from A's ----
            if (iB) {
                const unsigned u1B = K1B & VMASK, u2B = K2B & VMASK;
                const float u2fB = __uint_as_float(u2B);
                const bool uniqB = (u1B < u2B);
                int jtB = j1B;
                int kickB = __builtin_amdgcn_readlane(p, j1B - 1);
                if (!uniqB && kickB != 0) jtB = (int)(K2B & 63u) + 1;
                if (jtB != jtA) {                  // accept (proof in header)
                    if (uniqB)
                        v = sel_f32(1ull << (j1B - 1),
                                    v - (u2fB - __uint_as_float(u1B)), v);
                    if (jtB != j1B) kickB = __builtin_amdgcn_readlane(p, jtB - 1);
                    p = sel_i32(1ull << (jtB - 1), iB, p);
                    u = sel_f32(1ull << (iB - 1), u2fB, u);
                    if (kickB != 0) freerows |= 1ull << (kickB - 1);
                } else {
                    freerows |= 1ull << (iB - 1);  // collision: retry row iB
                }
            }
        }
    }

    // ---- Dijkstra phases for remaining free rows (identical to R12) ----
    while (freerows) {
        const int i = __ffsll(freerows);           // 1-based free row
        freerows &= freerows - 1;
        unsigned long long um = 0ull;              // used (selected) columns
        unsigned long long rowm = 1ull << (i - 1); // rows on the tree
        float d = FINF;                            // tentative distances
        int way = 0;                               // tree parent column (0=root)
        int vj0 = 0;                               // previous j1 (VGPR copy)
        float s = 0.0f - readlane_f(u, i - 1);     // s = D(i0) - u0[i0]
        uent = sel_f32(rowm, 0.0f, uent);          // root row entry distance = 0
        float aval = mat_get(alo, ahi, i - 1);     // row i (fake lanes -inf)
        int j1f = 0;
        float DT = 0.0f;
        for (int guard = 0; guard < NMAX; ++guard) {
            const float r_ = (0.0f - aval) - v;    // used/fake -> +inf
            const float cur = fmaxf(r_ + s, 0.0f); // clamp: keys stay ordered
            const float dn = fminf(d, cur);
            const unsigned key = (__float_as_uint(dn) & VMASK) | (unsigned)lane;
            const unsigned K = (unsigned)__builtin_amdgcn_readlane((int)dpp_umin6(key), 63);
            const int j1 = (int)(K & 63u) + 1;
            const int i0n = __builtin_amdgcn_readlane(p, j1 - 1); // p[j1]; 0 => free
            const float H = __uint_as_float(K & VMASK);           // delta (trunc)
            const unsigned long long mj = 1ull << (j1 - 1);
            const bool lt = cur < d;
            way  = lt ? vj0 : way;
            dsel = sel_f32(mj, dn, dsel);          // record selected distance
            d    = sel_f32(mj, FINF, dn);          // destroy selected column
            if (i0n == 0) { j1f = j1; DT = H; break; }
            um |= mj;
            rowm |= 1ull << (i0n - 1);
            uent = sel_f32(1ull << (i0n - 1), H, uent);   // row entry distance
            s = H - readlane_f(u, i0n - 1);
            aval = mat_get(alo, ahi, i0n - 1);
            aval = __int_as_float((int)sel_u32(um, NEGINF32, __float_as_int(aval)));
            vj0 = j1;
        }
        // ---- phase-end dual updates (equivalent to per-iteration +=/-=) ----
        v = sel_f32(um,   v + (dsel - DT), v);     // used columns
        u = sel_f32(rowm, u + (DT - uent), u);     // tree rows
        // ---- augment along way[] back to the root ----
        int j0 = j1f;
        while (j0 > 0) {
            const int j1w = __builtin_amdgcn_readlane(way, j0 - 1);
            const int newp = (j1w == 0) ? i : __builtin_amdgcn_readlane(p, j1w - 1);
            p = sel_i32(1ull << (j0 - 1), newp, p);
            j0 = j1w;
        }
    }

    // ---- fused loss: dis[i][j] from lane-held p; BCE in f32 like reference ----
    double lsum = 0.0;
    if (!trans) {
        #pragma unroll
        for (int i2 = 0; i2 < NMAX; ++i2) {
            const float pv = (i2 < 32) ? alo[i2] : ahi[i2 - 32];   // static extract
            const float gv = gtb[i2 * NMAX + lane];
            const float dis = (p == i2 + 1) ? 1.0f : 0.0f;
            float ali = dis + gv;
            if (ali > 1.0f) ali = 0.9f;
            const float pp = ali * pv;
            const float gg = ali * gv;
            const float lp  = fmaxf(logf(pp),    -100.0f);
            const float l1p = fmaxf(log1pf(-pp), -100.0f);
            const float bce = -(gg * lp + (1.0f - gg) * l1p);
            if (i2 < n1 && lane < n2) lsum += (double)bce;
        }
    } else {
        for (int i2 = 0; i2 < NMAX; ++i2) {
            const float pv = predb[i2 * NMAX + lane];
            const float gv = gtb[i2 * NMAX + lane];
            const int pi = __builtin_amdgcn_readlane(p, i2);
            const float dis = (pi - 1 == lane) ? 1.0f : 0.0f;
            float ali = dis + gv;
            if (ali > 1.0f) ali = 0.9f;
            const float pp = ali * pv;
            const float gg = ali * gv;
            const float lp  = fmaxf(logf(pp),    -100.0f);
            const float l1p = fmaxf(log1pf(-pp), -100.0f);
            const float bce = -(gg * lp + (1.0f - gg) * l1p);
            if (i2 < n1 && lane < n2) lsum += (double)bce;
        }
    }
    const double tsum = wave_sum_f64(lsum);
    if (lane == 0) partial[b] = tsum;
}

__global__ __launch_bounds__(256) void finalize_kernel(
    const double* __restrict__ partial, const int* __restrict__ n1s,
    float* __restrict__ out, int B)
{
    __shared__ double sred[256];
    __shared__ int    nred[256];
    const int t = threadIdx.x;
    double s = 0.0;
    int ns = 0;
    for (int bb = t; bb < B; bb += 256) { s += partial[bb]; ns += n1s[bb]; }
    sred[t] = s; nred[t] = ns;
    __syncthreads();
    for (int off = 128; off >= 1; off >>= 1) {
        if (t < off) { sred[t] += sred[t + off]; nred[t] += nred[t + off]; }
        __syncthreads();
    }
    if (t == 0) out[0] = (float)sred[0] / (float)nred[0];
}

extern "C" void kernel_launch(void* const* d_in, const int* in_sizes, int n_in,
                              void* d_out, int out_size, void* d_ws, size_t ws_size,
                              hipStream_t stream) {
    const float* pred = (const float*)d_in[0];   // [B,64,64] f32
    const float* gt   = (const float*)d_in[1];   // [B,64,64] f32
    const int* n1s    = (const int*)d_in[2];     // [B] i32
    const int* n2s    = (const int*)d_in[3];     // [B] i32
    float* out = (float*)d_out;                  // scalar f32
    double* partial = (double*)d_ws;             // B doubles (16 KB)
    const int B = in_sizes[2];

    hung_loss_kernel<<<B, 64, 0, stream>>>(pred, gt, n1s, n2s, partial);
    finalize_kernel<<<1, 256, 0, stream>>>(partial, n1s, out, B);
}